// Round 13
// baseline (119.634 us; speedup 1.0000x reference)
//
#include <hip/hip_runtime.h>
#include <hip/hip_bf16.h>
#include <cstdint>

typedef __attribute__((ext_vector_type(8))) __bf16 bf16x8;
typedef __attribute__((ext_vector_type(4))) float f32x4;
typedef unsigned short u16;
typedef unsigned int u32;

struct alignas(8) U16x4 { u16 x, y, z, w; };
struct alignas(8) U32x2 { u32 x, y; };

__device__ __forceinline__ u16 f2b(float x) {
    u32 u = __builtin_bit_cast(u32, x);
    u += 0x7fffu + ((u >> 16) & 1u);   // round-to-nearest-even
    return (u16)(u >> 16);
}
__device__ __forceinline__ u32 cvtpk(float lo, float hi) {
    u32 r;
    asm("v_cvt_pk_bf16_f32 %0, %1, %2" : "=v"(r) : "v"(lo), "v"(hi));
    return r;
}

#define LOG2E 1.44269504088896f

// ---------------- kernel 1: f32 -> bf16 convert (hidden + concat weights) ----
// extra last block pre-scales the additive mask by log2(e) (for exp2 in attn).
__global__ __launch_bounds__(256) void cvt_kernel(
    const float* __restrict__ hs,
    const float* __restrict__ wq, const float* __restrict__ wk, const float* __restrict__ wv,
    const float* __restrict__ amask,
    u16* __restrict__ hsb, u16* __restrict__ wb, float* __restrict__ amask2)
{
    if (blockIdx.x == 7168) {          // 4096 floats = 1024 float4 chunks
        int t = threadIdx.x;
        #pragma unroll
        for (int j = 0; j < 4; ++j) {
            float4 v = ((const float4*)amask)[t + j * 256];
            v.x *= LOG2E; v.y *= LOG2E; v.z *= LOG2E; v.w *= LOG2E;
            ((float4*)amask2)[t + j * 256] = v;
        }
        return;
    }
    int i = blockIdx.x * 256 + threadIdx.x;       // float4 chunk index, exact grid
    const float4* src; u16* dst; int off;
    if (i < 1048576) { src = (const float4*)hs; dst = hsb; off = i; }
    else {
        int j = i - 1048576;                      // 3 * 262144 chunks
        int w = j >> 18;
        int o = j & 262143;
        src = (const float4*)(w == 0 ? wq : (w == 1 ? wk : wv));
        dst = wb + w * 1048576;
        off = o;
    }
    float4 v = src[off];
    U16x4 r; r.x = f2b(v.x); r.y = f2b(v.y); r.z = f2b(v.z); r.w = f2b(v.w);
    *(U16x4*)(dst + off * 4) = r;
}

// ---------------- kernel 2: QKV GEMM  C[4096,3072] = A[4096,1024] * W[3072,1024]^T
// BK=32 double-buffered global_load_lds, {barrier; stage(t+1); compute(t)} loop.
// Q pre-scaled by 0.125*log2(e) (exp2 trick); V written transposed. ~31 us.
__global__ __launch_bounds__(256, 3) void qkv_gemm(
    const u16* __restrict__ A, const u16* __restrict__ W,
    const float* __restrict__ bq, const float* __restrict__ bk, const float* __restrict__ bv,
    u16* __restrict__ Qo, u16* __restrict__ Ko, u16* __restrict__ Vt)
{
    __shared__ u16 As[2][128 * 32];   // 8 KB per buffer
    __shared__ u16 Bs[2][128 * 32];
    const int tid = threadIdx.x;
    const int lane = tid & 63, wid = tid >> 6;
    const int wr = (wid >> 1) * 64, wc = (wid & 1) * 64;  // wave sub-tile origin
    const int g = lane >> 4, c = lane & 15;

    int lin = blockIdx.y * 24 + blockIdx.x;
    int wg = (lin & 7) * 96 + (lin >> 3);
    const int bn = wg >> 5;      // 0..23
    const int bm = wg & 31;      // 0..31

    f32x4 acc[4][4] = {};

#define GSTAGE(bf, k0)                                                              \
    {                                                                               \
        _Pragma("unroll") for (int i = 0; i < 2; ++i) {                             \
            int chunk = i * 256 + tid;                                              \
            int row = chunk >> 2, col = (chunk & 3) * 8;                            \
            const u16* ga = A + (bm * 128 + row) * 1024 + (k0) + col;               \
            const u16* gb = W + (bn * 128 + row) * 1024 + (k0) + col;               \
            u16* la = &As[bf][0] + (i * 256 + wid * 64) * 8;                        \
            u16* lb = &Bs[bf][0] + (i * 256 + wid * 64) * 8;                        \
            __builtin_amdgcn_global_load_lds((const __attribute__((address_space(1))) u32*)ga, \
                                             (__attribute__((address_space(3))) u32*)la, 16, 0, 0); \
            __builtin_amdgcn_global_load_lds((const __attribute__((address_space(1))) u32*)gb, \
                                             (__attribute__((address_space(3))) u32*)lb, 16, 0, 0); \
        }                                                                           \
    }

    GSTAGE(0, 0);

    int cur = 0;
    for (int t = 0; t < 32; ++t) {
        __syncthreads();              // stage(t) drained (issued one phase ago)
        if (t < 31) GSTAGE(cur ^ 1, (t + 1) * 32);   // overlaps compute below
        bf16x8 af[4], bf4[4];
        #pragma unroll
        for (int i = 0; i < 4; ++i)
            af[i] = *(const bf16x8*)(&As[cur][0] + (wr + i * 16 + c) * 32 + g * 8);
        #pragma unroll
        for (int j = 0; j < 4; ++j)
            bf4[j] = *(const bf16x8*)(&Bs[cur][0] + (wc + j * 16 + c) * 32 + g * 8);
        #pragma unroll
        for (int i = 0; i < 4; ++i)
            #pragma unroll
            for (int j = 0; j < 4; ++j)
                acc[i][j] = __builtin_amdgcn_mfma_f32_16x16x32_bf16(af[i], bf4[j], acc[i][j], 0, 0, 0);
        cur ^= 1;
    }
#undef GSTAGE

    const int region = bn >> 3;                      // 0=Q 1=K 2=V
    const float* bias = region == 0 ? bq : (region == 1 ? bk : bv);
    #pragma unroll
    for (int i = 0; i < 4; ++i) {
        int m0 = bm * 128 + wr + i * 16 + g * 4;
        int b = m0 >> 10, s0 = m0 & 1023;
        #pragma unroll
        for (int j = 0; j < 4; ++j) {
            int n = (bn & 7) * 128 + wc + j * 16 + c;
            float bb = bias[n];
            int h = n >> 6, d = n & 63;
            int bh = b * 16 + h;
            if (region == 2) {
                U16x4 pk;
                pk.x = f2b(acc[i][j][0] + bb);
                pk.y = f2b(acc[i][j][1] + bb);
                pk.z = f2b(acc[i][j][2] + bb);
                pk.w = f2b(acc[i][j][3] + bb);
                *(U16x4*)(Vt + (bh * 64 + d) * 1024 + s0) = pk;
            } else if (region == 1) {
                #pragma unroll
                for (int r = 0; r < 4; ++r)
                    Ko[(bh * 1024 + s0 + r) * 64 + d] = f2b(acc[i][j][r] + bb);
            } else {
                #pragma unroll
                for (int r = 0; r < 4; ++r)   // fold 1/sqrt(D) * log2(e) into Q
                    Qo[(bh * 1024 + s0 + r) * 64 + d] = f2b((acc[i][j][r] + bb) * (0.125f * LOG2E));
            }
        }
    }
}

// ---------------- kernel 3: fused attention, post-softmax multiplicative link mask
// Round-13 OCCUPANCY build: 512 blocks x 512 threads (8 waves x 16 q-rows =
// 128 q-rows/block). LDS = K dbuf 16K + V dbuf 16K + P 8x2K = 48 KB -> 3
// blocks/CU = 24 waves/CU (6/SIMD), up from 16 (R10/R12). Staging traffic
// halves (one 16 KB K+V tile serves 128 q-rows). VGPR ~56 <= cap 84 at
// __launch_bounds__(512,6) -> no spill. exp2 replaces exp (Q and mask carry
// the log2e factor) saving 16 v_mul/tile/wave. Otherwise R10's proven
// structure: both-sides XOR swizzles, P stride-64 bank-swizzled, setprio
// around PV, {barrier; stage(t+1); compute(t)} pipeline.
__global__ __launch_bounds__(512, 6) void attn_kernel(
    const u16* __restrict__ Q, const u16* __restrict__ K, const u16* __restrict__ Vt,
    const float* __restrict__ amask, const float* __restrict__ link,
    float* __restrict__ out)
{
    __shared__ u16 Ks[2][64 * 64];     // 8 KB per buffer
    __shared__ u16 Vs[2][64 * 64];     // 8 KB per buffer
    __shared__ u16 P[8][16 * 64];      // per-wave [q=16][k=64], XOR-swizzled banks
    const int tid = threadIdx.x;
    const int lane = tid & 63, wid = tid >> 6;
    const int g = lane >> 4, c = lane & 15;
    const int c7 = c & 7;

    // XCD swizzle: 512 blocks; XCD x owns logical x*64..x*64+63 = half a batch's
    // q-range (512 q-rows, 2 MB link slice) across all 16 heads.
    int hw = blockIdx.x;
    int logical = (hw & 7) * 64 + (hw >> 3);
    int b = logical >> 7;              // [0,4)
    int qt = (logical >> 4) & 7;       // [0,8) tiles of 128 q-rows
    int h = logical & 15;
    int bh = b * 16 + h;
    const int qbase = qt * 128 + wid * 16;

    const u16* Qh = Q + bh * 65536;
    const u16* Kh = K + bh * 65536;
    const u16* Vh = Vt + bh * 65536;
    const float* mk = amask + b * 1024;          // pre-scaled by log2(e)
    const float* lkq = link + (size_t)b * 1048576 + (size_t)(qbase + c) * 1024;

    bf16x8 qfx0 = *(const bf16x8*)(Qh + (qbase + c) * 64 + g * 8);
    bf16x8 qfx1 = *(const bf16x8*)(Qh + (qbase + c) * 64 + 32 + g * 8);

    float lsum = 0.f;
    f32x4 ctx[4] = {};
    u16* const Pb = &P[wid][0];

    // stage K+V kv-tile into buffer bf: 512+512 chunks of 16B across 512 threads
    // (one K chunk + one V chunk per thread). Source chunk-in-row XOR-swizzled so
    // LDS stays linear (rule #21); rows are 128 B -> needs it.
#define ASTAGE(bf, kv)                                                              \
    {                                                                               \
        int chunk = tid;                                                            \
        int row = chunk >> 3;                                                       \
        int scir = (chunk & 7) ^ (row & 7);                                         \
        const u16* gk = Kh + ((kv) + row) * 64 + scir * 8;                          \
        const u16* gv = Vh + row * 1024 + (kv) + scir * 8;                          \
        u16* lk = &Ks[bf][0] + (wid * 64) * 8;                                      \
        u16* lv = &Vs[bf][0] + (wid * 64) * 8;                                      \
        __builtin_amdgcn_global_load_lds((const __attribute__((address_space(1))) u32*)gk, \
                                         (__attribute__((address_space(3))) u32*)lk, 16, 0, 0); \
        __builtin_amdgcn_global_load_lds((const __attribute__((address_space(1))) u32*)gv, \
                                         (__attribute__((address_space(3))) u32*)lv, 16, 0, 0); \
    }

    ASTAGE(0, 0);

    int cur = 0;
    for (int t = 0; t < 16; ++t) {
        __syncthreads();               // stage(t) drained (issued one phase ago)
        if (t < 15) ASTAGE(cur ^ 1, (t + 1) * 64);  // overlaps compute below
        const int kv = t * 64;
        const u16* Kb = &Ks[cur][0];
        const u16* Vb = &Vs[cur][0];

        // hoist this tile's mask + link loads (independent of MFMA chain)
        f32x4 m4[4], lk4[4];
        #pragma unroll
        for (int kt = 0; kt < 4; ++kt) {
            m4[kt]  = *(const f32x4*)(mk  + kv + kt * 16 + g * 4);
            lk4[kt] = *(const f32x4*)(lkq + kv + kt * 16 + g * 4);
        }

        // ---- QK^T + exp2 + link, one 16-key group at a time ----
        #pragma unroll
        for (int kt = 0; kt < 4; ++kt) {
            bf16x8 kf0 = *(const bf16x8*)(Kb + (kt * 16 + c) * 64 + ((g)     ^ c7) * 8);
            bf16x8 kf1 = *(const bf16x8*)(Kb + (kt * 16 + c) * 64 + ((4 + g) ^ c7) * 8);
            f32x4 sc = {};
            sc = __builtin_amdgcn_mfma_f32_16x16x32_bf16(kf0, qfx0, sc, 0, 0, 0);
            sc = __builtin_amdgcn_mfma_f32_16x16x32_bf16(kf1, qfx1, sc, 0, 0, 0);
            float e0 = exp2f(sc[0] + m4[kt][0]);   // Q,mask carry log2(e)
            float e1 = exp2f(sc[1] + m4[kt][1]);
            float e2 = exp2f(sc[2] + m4[kt][2]);
            float e3 = exp2f(sc[3] + m4[kt][3]);
            lsum += (e0 + e1) + (e2 + e3);
            U32x2 pw;
            pw.x = cvtpk(e0 * lk4[kt][0], e1 * lk4[kt][1]);
            pw.y = cvtpk(e2 * lk4[kt][2], e3 * lk4[kt][3]);
            // P write: row c, 8B-chunk (kt*4+g) ^ ((c&7)<<1)  [bank-uniform]
            *(U32x2*)(Pb + c * 64 + (((kt * 4 + g) ^ (c7 << 1)) * 4)) = pw;
        }
        // ---- PV: P from per-wave LDS (in-order DS pipe), V from staged tile ----
        __builtin_amdgcn_s_setprio(1);
        #pragma unroll
        for (int kk = 0; kk < 2; ++kk) {
            // P read: row c, 16B pair starting at chunk (kk*8+g*2) ^ ((c&7)<<1)
            bf16x8 pf = *(const bf16x8*)(Pb + c * 64 + (((kk * 8 + g * 2) ^ (c7 << 1)) * 4));
            #pragma unroll
            for (int dt = 0; dt < 4; ++dt) {
                bf16x8 vf = *(const bf16x8*)(Vb + (dt * 16 + c) * 64 + ((kk * 4 + g) ^ c7) * 8);
                ctx[dt] = __builtin_amdgcn_mfma_f32_16x16x32_bf16(pf, vf, ctx[dt], 0, 0, 0);
            }
        }
        __builtin_amdgcn_s_setprio(0);
        cur ^= 1;
    }
#undef ASTAGE

    lsum += __shfl_xor(lsum, 16, 64);
    lsum += __shfl_xor(lsum, 32, 64);

    #pragma unroll
    for (int r = 0; r < 4; ++r) {
        float inv = 1.0f / __shfl(lsum, g * 4 + r, 16);
        int q = qbase + g * 4 + r;
        float* orow = out + (size_t)b * 1048576 + (size_t)q * 1024 + h * 64;
        #pragma unroll
        for (int dt = 0; dt < 4; ++dt)
            orow[dt * 16 + c] = ctx[dt][r] * inv;
    }
}

extern "C" void kernel_launch(void* const* d_in, const int* in_sizes, int n_in,
                              void* d_out, int out_size, void* d_ws, size_t ws_size,
                              hipStream_t stream)
{
    (void)in_sizes; (void)n_in; (void)out_size; (void)ws_size;
    const float* hs    = (const float*)d_in[0];
    const float* amask = (const float*)d_in[1];
    const float* link  = (const float*)d_in[2];
    const float* Wq    = (const float*)d_in[3];
    const float* bq    = (const float*)d_in[4];
    const float* Wk    = (const float*)d_in[5];
    const float* bk    = (const float*)d_in[6];
    const float* Wv    = (const float*)d_in[7];
    const float* bv    = (const float*)d_in[8];
    float* out = (float*)d_out;

    char* ws = (char*)d_ws;
    u16* hsb = (u16*)ws;                   // 8 MiB  [4096][1024] bf16
    u16* wb  = (u16*)(ws + (8u  << 20));   // 6 MiB  [3072][1024] bf16 (Wq|Wk|Wv)
    u16* Qb  = (u16*)(ws + (14u << 20));   // 8 MiB  [B,H,S,64]  (pre-scaled)
    u16* Kb  = (u16*)(ws + (22u << 20));   // 8 MiB  [B,H,S,64]
    u16* Vtb = (u16*)(ws + (30u << 20));   // 8 MiB  [B,H,64,S]
    float* amask2 = (float*)(ws + (38u << 20));  // 16 KB scaled mask

    cvt_kernel<<<7169, 256, 0, stream>>>(hs, Wq, Wk, Wv, amask, hsb, wb, amask2);
    qkv_gemm<<<dim3(24, 32), 256, 0, stream>>>(hsb, wb, bq, bk, bv, Qb, Kb, Vtb);
    attn_kernel<<<512, 512, 0, stream>>>(Qb, Kb, Vtb, amask2, link, out);
}

// Round 14
// 91.576 us; speedup vs baseline: 1.3064x; 1.3064x over previous
//
#include <hip/hip_runtime.h>
#include <hip/hip_bf16.h>
#include <cstdint>

typedef __attribute__((ext_vector_type(8))) __bf16 bf16x8;
typedef __attribute__((ext_vector_type(4))) float f32x4;
typedef unsigned short u16;
typedef unsigned int u32;

struct alignas(8) U16x4 { u16 x, y, z, w; };
struct alignas(8) U32x2 { u32 x, y; };

__device__ __forceinline__ u16 f2b(float x) {
    u32 u = __builtin_bit_cast(u32, x);
    u += 0x7fffu + ((u >> 16) & 1u);   // round-to-nearest-even
    return (u16)(u >> 16);
}
__device__ __forceinline__ u32 cvtpk(float lo, float hi) {
    u32 r;
    asm("v_cvt_pk_bf16_f32 %0, %1, %2" : "=v"(r) : "v"(lo), "v"(hi));
    return r;
}

#define LOG2E 1.44269504088896f

// ---------------- kernel 1: f32 -> bf16 convert (hidden + concat weights) ----
// extra last block pre-scales the additive mask by log2(e) (for exp2 in attn).
__global__ __launch_bounds__(256) void cvt_kernel(
    const float* __restrict__ hs,
    const float* __restrict__ wq, const float* __restrict__ wk, const float* __restrict__ wv,
    const float* __restrict__ amask,
    u16* __restrict__ hsb, u16* __restrict__ wb, float* __restrict__ amask2)
{
    if (blockIdx.x == 7168) {          // 4096 floats = 1024 float4 chunks
        int t = threadIdx.x;
        #pragma unroll
        for (int j = 0; j < 4; ++j) {
            float4 v = ((const float4*)amask)[t + j * 256];
            v.x *= LOG2E; v.y *= LOG2E; v.z *= LOG2E; v.w *= LOG2E;
            ((float4*)amask2)[t + j * 256] = v;
        }
        return;
    }
    int i = blockIdx.x * 256 + threadIdx.x;       // float4 chunk index, exact grid
    const float4* src; u16* dst; int off;
    if (i < 1048576) { src = (const float4*)hs; dst = hsb; off = i; }
    else {
        int j = i - 1048576;                      // 3 * 262144 chunks
        int w = j >> 18;
        int o = j & 262143;
        src = (const float4*)(w == 0 ? wq : (w == 1 ? wk : wv));
        dst = wb + w * 1048576;
        off = o;
    }
    float4 v = src[off];
    U16x4 r; r.x = f2b(v.x); r.y = f2b(v.y); r.z = f2b(v.z); r.w = f2b(v.w);
    *(U16x4*)(dst + off * 4) = r;
}

// ---------------- kernel 2: QKV GEMM  C[4096,3072] = A[4096,1024] * W[3072,1024]^T
// BK=32 double-buffered global_load_lds, {barrier; stage(t+1); compute(t)} loop.
// Q pre-scaled by 0.125*log2(e) (exp2 trick); V written transposed. ~31 us.
__global__ __launch_bounds__(256, 3) void qkv_gemm(
    const u16* __restrict__ A, const u16* __restrict__ W,
    const float* __restrict__ bq, const float* __restrict__ bk, const float* __restrict__ bv,
    u16* __restrict__ Qo, u16* __restrict__ Ko, u16* __restrict__ Vt)
{
    __shared__ u16 As[2][128 * 32];   // 8 KB per buffer
    __shared__ u16 Bs[2][128 * 32];
    const int tid = threadIdx.x;
    const int lane = tid & 63, wid = tid >> 6;
    const int wr = (wid >> 1) * 64, wc = (wid & 1) * 64;  // wave sub-tile origin
    const int g = lane >> 4, c = lane & 15;

    int lin = blockIdx.y * 24 + blockIdx.x;
    int wg = (lin & 7) * 96 + (lin >> 3);
    const int bn = wg >> 5;      // 0..23
    const int bm = wg & 31;      // 0..31

    f32x4 acc[4][4] = {};

#define GSTAGE(bf, k0)                                                              \
    {                                                                               \
        _Pragma("unroll") for (int i = 0; i < 2; ++i) {                             \
            int chunk = i * 256 + tid;                                              \
            int row = chunk >> 2, col = (chunk & 3) * 8;                            \
            const u16* ga = A + (bm * 128 + row) * 1024 + (k0) + col;               \
            const u16* gb = W + (bn * 128 + row) * 1024 + (k0) + col;               \
            u16* la = &As[bf][0] + (i * 256 + wid * 64) * 8;                        \
            u16* lb = &Bs[bf][0] + (i * 256 + wid * 64) * 8;                        \
            __builtin_amdgcn_global_load_lds((const __attribute__((address_space(1))) u32*)ga, \
                                             (__attribute__((address_space(3))) u32*)la, 16, 0, 0); \
            __builtin_amdgcn_global_load_lds((const __attribute__((address_space(1))) u32*)gb, \
                                             (__attribute__((address_space(3))) u32*)lb, 16, 0, 0); \
        }                                                                           \
    }

    GSTAGE(0, 0);

    int cur = 0;
    for (int t = 0; t < 32; ++t) {
        __syncthreads();              // stage(t) drained (issued one phase ago)
        if (t < 31) GSTAGE(cur ^ 1, (t + 1) * 32);   // overlaps compute below
        bf16x8 af[4], bf4[4];
        #pragma unroll
        for (int i = 0; i < 4; ++i)
            af[i] = *(const bf16x8*)(&As[cur][0] + (wr + i * 16 + c) * 32 + g * 8);
        #pragma unroll
        for (int j = 0; j < 4; ++j)
            bf4[j] = *(const bf16x8*)(&Bs[cur][0] + (wc + j * 16 + c) * 32 + g * 8);
        #pragma unroll
        for (int i = 0; i < 4; ++i)
            #pragma unroll
            for (int j = 0; j < 4; ++j)
                acc[i][j] = __builtin_amdgcn_mfma_f32_16x16x32_bf16(af[i], bf4[j], acc[i][j], 0, 0, 0);
        cur ^= 1;
    }
#undef GSTAGE

    const int region = bn >> 3;                      // 0=Q 1=K 2=V
    const float* bias = region == 0 ? bq : (region == 1 ? bk : bv);
    #pragma unroll
    for (int i = 0; i < 4; ++i) {
        int m0 = bm * 128 + wr + i * 16 + g * 4;
        int b = m0 >> 10, s0 = m0 & 1023;
        #pragma unroll
        for (int j = 0; j < 4; ++j) {
            int n = (bn & 7) * 128 + wc + j * 16 + c;
            float bb = bias[n];
            int h = n >> 6, d = n & 63;
            int bh = b * 16 + h;
            if (region == 2) {
                U16x4 pk;
                pk.x = f2b(acc[i][j][0] + bb);
                pk.y = f2b(acc[i][j][1] + bb);
                pk.z = f2b(acc[i][j][2] + bb);
                pk.w = f2b(acc[i][j][3] + bb);
                *(U16x4*)(Vt + (bh * 64 + d) * 1024 + s0) = pk;
            } else if (region == 1) {
                #pragma unroll
                for (int r = 0; r < 4; ++r)
                    Ko[(bh * 1024 + s0 + r) * 64 + d] = f2b(acc[i][j][r] + bb);
            } else {
                #pragma unroll
                for (int r = 0; r < 4; ++r)   // fold 1/sqrt(D) * log2(e) into Q
                    Qo[(bh * 1024 + s0 + r) * 64 + d] = f2b((acc[i][j][r] + bb) * (0.125f * LOG2E));
            }
        }
    }
}

// ---------------- kernel 3: fused attention, post-softmax multiplicative link mask
// Round-14: LINK MASK STAGED THROUGH LDS. R12's exp phase read link with per-lane
// row-strided float4s (one instr -> 16 distinct cachelines, ~64 scattered L2
// transactions per wave-tile ON the serial chain). Now link rides the same
// fire-and-forget global_load_lds dbuf pipeline as K/V: coalesced staging,
// drained free at the barrier, LDS-latency reads in exp. KVBLK=32 so LDS =
// K(2x4K)+V(2x4K)+linkf32(2x8K)+P(4x1K) = 36 KB -> 4 blocks/CU at VGPR<=64.
// All XOR swizzles rederived for narrow rows (2-way banks everywhere):
//   K  [32k][64d]: LDS[r][p]=src[r][p^(r&7)],     read p=(g|4+g)^(c&7)   (=R12)
//   V  [64d][32k]: LDS[r][p]=src[r][p^((r>>1)&3)],read p=g^((c>>1)&3)
//   L  [64q][32k]: LDS[r][p]=src[r][p^(r&7)],     read p=(kt*4+g)^(c&7)
//   P  [16q][8 quads]: quad w stored at w^(((c>>1)&3)<<1); b128 read lands at
//      (g^((c>>1)&3))*8 -- write/read verified consistent.
// 1024 blocks x 4 waves x 16 q-rows, 32 tiles of 32 keys, exp2 path.
__global__ __launch_bounds__(256, 4) void attn_kernel(
    const u16* __restrict__ Q, const u16* __restrict__ K, const u16* __restrict__ Vt,
    const float* __restrict__ amask, const float* __restrict__ link,
    float* __restrict__ out)
{
    __shared__ u16 Ks[2][32 * 64];     // 4 KB per buffer
    __shared__ u16 Vs[2][64 * 32];     // 4 KB per buffer
    __shared__ float Ls[2][64 * 32];   // 8 KB per buffer (link f32)
    __shared__ u16 P[4][16 * 32];      // 1 KB per wave
    const int tid = threadIdx.x;
    const int lane = tid & 63, wid = tid >> 6;
    const int g = lane >> 4, c = lane & 15;
    const int c7 = c & 7;
    const int s2 = (c >> 1) & 3;       // 2-bit spread code for V/P

    // XCD swizzle: 1024 blocks; XCD x owns logical x*128..x*128+127.
    int hw = blockIdx.x;
    int logical = (hw & 7) * 128 + (hw >> 3);
    int b = logical >> 8;              // [0,4)
    int qt = (logical >> 4) & 15;      // [0,16) tiles of 64 q-rows
    int h = logical & 15;
    int bh = b * 16 + h;
    const int qbase = qt * 64 + wid * 16;

    const u16* Qh = Q + bh * 65536;
    const u16* Kh = K + bh * 65536;
    const u16* Vh = Vt + bh * 65536;
    const float* mk = amask + b * 1024;            // pre-scaled by log2(e)
    const float* Lq = link + (size_t)b * 1048576 + (size_t)(qt * 64) * 1024;

    bf16x8 qfx0 = *(const bf16x8*)(Qh + (qbase + c) * 64 + g * 8);
    bf16x8 qfx1 = *(const bf16x8*)(Qh + (qbase + c) * 64 + 32 + g * 8);

    float lsum = 0.f;
    f32x4 ctx[4] = {};
    u16* const Pb = &P[wid][0];

    // stage K (256 chunks), V (256), link (512) -- 4 global_load_lds per thread.
    // All sources pre-swizzled so linear LDS + swizzled reads match (rule #21).
#define ASTAGE(bf, kv)                                                              \
    {                                                                               \
        int krow = tid >> 3, kcir = (tid & 7) ^ (krow & 7);                         \
        const u16* gk = Kh + ((kv) + krow) * 64 + kcir * 8;                         \
        __builtin_amdgcn_global_load_lds((const __attribute__((address_space(1))) u32*)gk, \
            (__attribute__((address_space(3))) u32*)(&Ks[bf][0] + wid * 512), 16, 0, 0); \
        int vrow = tid >> 2, vcir = (tid & 3) ^ ((vrow >> 1) & 3);                  \
        const u16* gv = Vh + vrow * 1024 + (kv) + vcir * 8;                         \
        __builtin_amdgcn_global_load_lds((const __attribute__((address_space(1))) u32*)gv, \
            (__attribute__((address_space(3))) u32*)(&Vs[bf][0] + wid * 512), 16, 0, 0); \
        int lrow0 = tid >> 3, lcir0 = (tid & 7) ^ (lrow0 & 7);                      \
        const float* gl0 = Lq + lrow0 * 1024 + (kv) + lcir0 * 4;                    \
        __builtin_amdgcn_global_load_lds((const __attribute__((address_space(1))) u32*)gl0, \
            (__attribute__((address_space(3))) u32*)(&Ls[bf][0] + wid * 256), 16, 0, 0); \
        int lc1 = 256 + tid;                                                        \
        int lrow1 = lc1 >> 3, lcir1 = (lc1 & 7) ^ (lrow1 & 7);                      \
        const float* gl1 = Lq + lrow1 * 1024 + (kv) + lcir1 * 4;                    \
        __builtin_amdgcn_global_load_lds((const __attribute__((address_space(1))) u32*)gl1, \
            (__attribute__((address_space(3))) u32*)(&Ls[bf][0] + 1024 + wid * 256), 16, 0, 0); \
    }

    ASTAGE(0, 0);

    int cur = 0;
    for (int t = 0; t < 32; ++t) {
        __syncthreads();               // stage(t) drained (issued one phase ago)
        if (t < 31) ASTAGE(cur ^ 1, (t + 1) * 32);  // overlaps compute below
        const int kv = t * 32;
        const u16* Kb = &Ks[cur][0];
        const u16* Vb = &Vs[cur][0];
        const float* Lb = &Ls[cur][0];

        // ---- QK^T + exp2 + link, one 16-key group at a time ----
        #pragma unroll
        for (int kt = 0; kt < 2; ++kt) {
            bf16x8 kf0 = *(const bf16x8*)(Kb + (kt * 16 + c) * 64 + ((g)     ^ c7) * 8);
            bf16x8 kf1 = *(const bf16x8*)(Kb + (kt * 16 + c) * 64 + ((4 + g) ^ c7) * 8);
            f32x4 sc = {};
            sc = __builtin_amdgcn_mfma_f32_16x16x32_bf16(kf0, qfx0, sc, 0, 0, 0);
            sc = __builtin_amdgcn_mfma_f32_16x16x32_bf16(kf1, qfx1, sc, 0, 0, 0);
            f32x4 m4  = *(const f32x4*)(mk + kv + kt * 16 + g * 4);   // broadcast, cheap
            f32x4 lk4 = *(const f32x4*)(Lb + (wid * 16 + c) * 32 + (((kt * 4 + g) ^ c7)) * 4);
            float e0 = exp2f(sc[0] + m4[0]);
            float e1 = exp2f(sc[1] + m4[1]);
            float e2 = exp2f(sc[2] + m4[2]);
            float e3 = exp2f(sc[3] + m4[3]);
            lsum += (e0 + e1) + (e2 + e3);
            U32x2 pw;
            pw.x = cvtpk(e0 * lk4[0], e1 * lk4[1]);
            pw.y = cvtpk(e2 * lk4[2], e3 * lk4[3]);
            *(U32x2*)(Pb + c * 32 + (((kt * 4 + g) ^ (s2 << 1)) * 4)) = pw;
        }
        // ---- PV: P from per-wave LDS (in-order DS pipe), V from staged tile ----
        __builtin_amdgcn_s_setprio(1);
        bf16x8 pf = *(const bf16x8*)(Pb + c * 32 + ((g ^ s2) * 8));
        #pragma unroll
        for (int dt = 0; dt < 4; ++dt) {
            bf16x8 vf = *(const bf16x8*)(Vb + (dt * 16 + c) * 32 + ((g ^ s2) * 8));
            ctx[dt] = __builtin_amdgcn_mfma_f32_16x16x32_bf16(pf, vf, ctx[dt], 0, 0, 0);
        }
        __builtin_amdgcn_s_setprio(0);
        cur ^= 1;
    }
#undef ASTAGE

    lsum += __shfl_xor(lsum, 16, 64);
    lsum += __shfl_xor(lsum, 32, 64);

    #pragma unroll
    for (int r = 0; r < 4; ++r) {
        float inv = 1.0f / __shfl(lsum, g * 4 + r, 16);
        int q = qbase + g * 4 + r;
        float* orow = out + (size_t)b * 1048576 + (size_t)q * 1024 + h * 64;
        #pragma unroll
        for (int dt = 0; dt < 4; ++dt)
            orow[dt * 16 + c] = ctx[dt][r] * inv;
    }
}

extern "C" void kernel_launch(void* const* d_in, const int* in_sizes, int n_in,
                              void* d_out, int out_size, void* d_ws, size_t ws_size,
                              hipStream_t stream)
{
    (void)in_sizes; (void)n_in; (void)out_size; (void)ws_size;
    const float* hs    = (const float*)d_in[0];
    const float* amask = (const float*)d_in[1];
    const float* link  = (const float*)d_in[2];
    const float* Wq    = (const float*)d_in[3];
    const float* bq    = (const float*)d_in[4];
    const float* Wk    = (const float*)d_in[5];
    const float* bk    = (const float*)d_in[6];
    const float* Wv    = (const float*)d_in[7];
    const float* bv    = (const float*)d_in[8];
    float* out = (float*)d_out;

    char* ws = (char*)d_ws;
    u16* hsb = (u16*)ws;                   // 8 MiB  [4096][1024] bf16
    u16* wb  = (u16*)(ws + (8u  << 20));   // 6 MiB  [3072][1024] bf16 (Wq|Wk|Wv)
    u16* Qb  = (u16*)(ws + (14u << 20));   // 8 MiB  [B,H,S,64]  (pre-scaled)
    u16* Kb  = (u16*)(ws + (22u << 20));   // 8 MiB  [B,H,S,64]
    u16* Vtb = (u16*)(ws + (30u << 20));   // 8 MiB  [B,H,64,S]
    float* amask2 = (float*)(ws + (38u << 20));  // 16 KB scaled mask

    cvt_kernel<<<7169, 256, 0, stream>>>(hs, Wq, Wk, Wv, amask, hsb, wb, amask2);
    qkv_gemm<<<dim3(24, 32), 256, 0, stream>>>(hsb, wb, bq, bk, bv, Qb, Kb, Vtb);
    attn_kernel<<<1024, 256, 0, stream>>>(Qb, Kb, Vtb, amask2, link, out);
}

// Round 15
// 86.791 us; speedup vs baseline: 1.3784x; 1.0551x over previous
//
#include <hip/hip_runtime.h>
#include <hip/hip_bf16.h>
#include <cstdint>

typedef __attribute__((ext_vector_type(8))) __bf16 bf16x8;
typedef __attribute__((ext_vector_type(4))) float f32x4;
typedef unsigned short u16;
typedef unsigned int u32;

struct alignas(8) U16x4 { u16 x, y, z, w; };
struct alignas(8) U32x2 { u32 x, y; };

__device__ __forceinline__ u16 f2b(float x) {
    u32 u = __builtin_bit_cast(u32, x);
    u += 0x7fffu + ((u >> 16) & 1u);   // round-to-nearest-even
    return (u16)(u >> 16);
}
__device__ __forceinline__ u32 cvtpk(float lo, float hi) {
    u32 r;
    asm("v_cvt_pk_bf16_f32 %0, %1, %2" : "=v"(r) : "v"(lo), "v"(hi));
    return r;
}
__device__ __forceinline__ float vexp2(float x) {   // raw v_exp_f32 (native 2^x)
    float r;
    asm("v_exp_f32 %0, %1" : "=v"(r) : "v"(x));
    return r;
}

#define LOG2E 1.44269504088896f

// ---------------- kernel 1: f32 -> bf16 convert (hidden + concat weights) ----
// extra last block pre-scales the additive mask by log2(e) (for exp2 in attn).
__global__ __launch_bounds__(256) void cvt_kernel(
    const float* __restrict__ hs,
    const float* __restrict__ wq, const float* __restrict__ wk, const float* __restrict__ wv,
    const float* __restrict__ amask,
    u16* __restrict__ hsb, u16* __restrict__ wb, float* __restrict__ amask2)
{
    if (blockIdx.x == 7168) {          // 4096 floats = 1024 float4 chunks
        int t = threadIdx.x;
        #pragma unroll
        for (int j = 0; j < 4; ++j) {
            float4 v = ((const float4*)amask)[t + j * 256];
            v.x *= LOG2E; v.y *= LOG2E; v.z *= LOG2E; v.w *= LOG2E;
            ((float4*)amask2)[t + j * 256] = v;
        }
        return;
    }
    int i = blockIdx.x * 256 + threadIdx.x;       // float4 chunk index, exact grid
    const float4* src; u16* dst; int off;
    if (i < 1048576) { src = (const float4*)hs; dst = hsb; off = i; }
    else {
        int j = i - 1048576;                      // 3 * 262144 chunks
        int w = j >> 18;
        int o = j & 262143;
        src = (const float4*)(w == 0 ? wq : (w == 1 ? wk : wv));
        dst = wb + w * 1048576;
        off = o;
    }
    float4 v = src[off];
    U16x4 r; r.x = f2b(v.x); r.y = f2b(v.y); r.z = f2b(v.z); r.w = f2b(v.w);
    *(U16x4*)(dst + off * 4) = r;
}

// ---------------- kernel 2: QKV GEMM  C[4096,3072] = A[4096,1024] * W[3072,1024]^T
// BK=32 double-buffered global_load_lds, {barrier; stage(t+1); compute(t)} loop.
// Q pre-scaled by 0.125*log2(e) (exp2 trick); V written transposed. ~27-31 us.
__global__ __launch_bounds__(256, 3) void qkv_gemm(
    const u16* __restrict__ A, const u16* __restrict__ W,
    const float* __restrict__ bq, const float* __restrict__ bk, const float* __restrict__ bv,
    u16* __restrict__ Qo, u16* __restrict__ Ko, u16* __restrict__ Vt)
{
    __shared__ u16 As[2][128 * 32];   // 8 KB per buffer
    __shared__ u16 Bs[2][128 * 32];
    const int tid = threadIdx.x;
    const int lane = tid & 63, wid = tid >> 6;
    const int wr = (wid >> 1) * 64, wc = (wid & 1) * 64;  // wave sub-tile origin
    const int g = lane >> 4, c = lane & 15;

    int lin = blockIdx.y * 24 + blockIdx.x;
    int wg = (lin & 7) * 96 + (lin >> 3);
    const int bn = wg >> 5;      // 0..23
    const int bm = wg & 31;      // 0..31

    f32x4 acc[4][4] = {};

#define GSTAGE(bf, k0)                                                              \
    {                                                                               \
        _Pragma("unroll") for (int i = 0; i < 2; ++i) {                             \
            int chunk = i * 256 + tid;                                              \
            int row = chunk >> 2, col = (chunk & 3) * 8;                            \
            const u16* ga = A + (bm * 128 + row) * 1024 + (k0) + col;               \
            const u16* gb = W + (bn * 128 + row) * 1024 + (k0) + col;               \
            u16* la = &As[bf][0] + (i * 256 + wid * 64) * 8;                        \
            u16* lb = &Bs[bf][0] + (i * 256 + wid * 64) * 8;                        \
            __builtin_amdgcn_global_load_lds((const __attribute__((address_space(1))) u32*)ga, \
                                             (__attribute__((address_space(3))) u32*)la, 16, 0, 0); \
            __builtin_amdgcn_global_load_lds((const __attribute__((address_space(1))) u32*)gb, \
                                             (__attribute__((address_space(3))) u32*)lb, 16, 0, 0); \
        }                                                                           \
    }

    GSTAGE(0, 0);

    int cur = 0;
    for (int t = 0; t < 32; ++t) {
        __syncthreads();              // stage(t) drained (issued one phase ago)
        if (t < 31) GSTAGE(cur ^ 1, (t + 1) * 32);   // overlaps compute below
        bf16x8 af[4], bf4[4];
        #pragma unroll
        for (int i = 0; i < 4; ++i)
            af[i] = *(const bf16x8*)(&As[cur][0] + (wr + i * 16 + c) * 32 + g * 8);
        #pragma unroll
        for (int j = 0; j < 4; ++j)
            bf4[j] = *(const bf16x8*)(&Bs[cur][0] + (wc + j * 16 + c) * 32 + g * 8);
        #pragma unroll
        for (int i = 0; i < 4; ++i)
            #pragma unroll
            for (int j = 0; j < 4; ++j)
                acc[i][j] = __builtin_amdgcn_mfma_f32_16x16x32_bf16(af[i], bf4[j], acc[i][j], 0, 0, 0);
        cur ^= 1;
    }
#undef GSTAGE

    const int region = bn >> 3;                      // 0=Q 1=K 2=V
    const float* bias = region == 0 ? bq : (region == 1 ? bk : bv);
    #pragma unroll
    for (int i = 0; i < 4; ++i) {
        int m0 = bm * 128 + wr + i * 16 + g * 4;
        int b = m0 >> 10, s0 = m0 & 1023;
        #pragma unroll
        for (int j = 0; j < 4; ++j) {
            int n = (bn & 7) * 128 + wc + j * 16 + c;
            float bb = bias[n];
            int h = n >> 6, d = n & 63;
            int bh = b * 16 + h;
            if (region == 2) {
                U16x4 pk;
                pk.x = f2b(acc[i][j][0] + bb);
                pk.y = f2b(acc[i][j][1] + bb);
                pk.z = f2b(acc[i][j][2] + bb);
                pk.w = f2b(acc[i][j][3] + bb);
                *(U16x4*)(Vt + (bh * 64 + d) * 1024 + s0) = pk;
            } else if (region == 1) {
                #pragma unroll
                for (int r = 0; r < 4; ++r)
                    Ko[(bh * 1024 + s0 + r) * 64 + d] = f2b(acc[i][j][r] + bb);
            } else {
                #pragma unroll
                for (int r = 0; r < 4; ++r)   // fold 1/sqrt(D) * log2(e) into Q
                    Qo[(bh * 1024 + s0 + r) * 64 + d] = f2b((acc[i][j][r] + bb) * (0.125f * LOG2E));
            }
        }
    }
}

// ---------------- kernel 3: fused attention, post-softmax multiplicative link mask
// Round-15 = R14 structure (K/V/link LDS-staged dbuf, KVBLK=32, 36 KB, 1024
// blocks x 4 waves x 16 q-rows, 4 blocks/CU) with VALU-diet:
//  - kv loop 2x-unrolled with STATIC buffer indices: all LDS read/write
//    addresses are loop-invariant per expansion (no runtime `cur` adds; the
//    swizzle XOR chains hoist out of the loop).
//  - staging source pointers ADVANCE by fixed strides (1 add each/tile)
//    instead of full row*stride+kv+cir recomputation.
//  - raw v_exp_f32 inline asm (native 2^x; bypasses libm wrapper).
// No new cross-barrier register state -> VGPR stays ~52-64, no spill.
__global__ __launch_bounds__(256, 4) void attn_kernel(
    const u16* __restrict__ Q, const u16* __restrict__ K, const u16* __restrict__ Vt,
    const float* __restrict__ amask, const float* __restrict__ link,
    float* __restrict__ out)
{
    __shared__ u16 Ks[2][32 * 64];     // 4 KB per buffer
    __shared__ u16 Vs[2][64 * 32];     // 4 KB per buffer
    __shared__ float Ls[2][64 * 32];   // 8 KB per buffer (link f32)
    __shared__ u16 P[4][16 * 32];      // 1 KB per wave
    const int tid = threadIdx.x;
    const int lane = tid & 63, wid = tid >> 6;
    const int g = lane >> 4, c = lane & 15;
    const int c7 = c & 7;
    const int s2 = (c >> 1) & 3;       // 2-bit spread code for V/P

    // XCD swizzle: 1024 blocks; XCD x owns logical x*128..x*128+127.
    int hw = blockIdx.x;
    int logical = (hw & 7) * 128 + (hw >> 3);
    int b = logical >> 8;              // [0,4)
    int qt = (logical >> 4) & 15;      // [0,16) tiles of 64 q-rows
    int h = logical & 15;
    int bh = b * 16 + h;
    const int qbase = qt * 64 + wid * 16;

    const u16* Qh = Q + bh * 65536;
    const u16* Kh = K + bh * 65536;
    const u16* Vh = Vt + bh * 65536;
    const float* Lq = link + (size_t)b * 1048576 + (size_t)(qt * 64) * 1024;

    bf16x8 qfx0 = *(const bf16x8*)(Qh + (qbase + c) * 64 + g * 8);
    bf16x8 qfx1 = *(const bf16x8*)(Qh + (qbase + c) * 64 + 32 + g * 8);

    float lsum = 0.f;
    f32x4 ctx[4] = {};
    u16* const Pb = &P[wid][0];

    // staging thread roles (loop-invariant)
    const int krow = tid >> 3, kcir = (tid & 7) ^ (krow & 7);
    const int vrow = tid >> 2, vcir = (tid & 3) ^ ((vrow >> 1) & 3);
    const int lr1i = (256 + tid) >> 3;
    const int lc1 = ((256 + tid) & 7) ^ (lr1i & 7);
    // advancing source pointers (point at the NEXT tile to stage)
    const u16* gk   = Kh + krow * 64 + kcir * 8;         // += 2048/tile
    const u16* gv   = Vh + vrow * 1024 + vcir * 8;       // += 32/tile
    const float* gl0 = Lq + krow * 1024 + kcir * 4;      // += 32/tile (rows 0-31)
    const float* gl1 = Lq + lr1i * 1024 + lc1 * 4;       // += 32/tile (rows 32-63)
    const float* mkP = amask + b * 1024;                 // += 32/tile (log2e-scaled)

#define AS3(p) (__attribute__((address_space(3))) u32*)(p)
#define AS1(p) (const __attribute__((address_space(1))) u32*)(p)
#define ISSUE_STAGE(B)                                                              \
    {                                                                               \
        __builtin_amdgcn_global_load_lds(AS1(gk),  AS3(&Ks[B][0] + wid * 512), 16, 0, 0); \
        __builtin_amdgcn_global_load_lds(AS1(gv),  AS3(&Vs[B][0] + wid * 512), 16, 0, 0); \
        __builtin_amdgcn_global_load_lds(AS1(gl0), AS3(&Ls[B][0] + wid * 256), 16, 0, 0); \
        __builtin_amdgcn_global_load_lds(AS1(gl1), AS3(&Ls[B][0] + 1024 + wid * 256), 16, 0, 0); \
        gk += 2048; gv += 32; gl0 += 32; gl1 += 32;                                 \
    }

    // one kv-tile on STATIC buffer index B; stages tile T+1 into B^1.
#define ATILE(B, T)                                                                 \
    {                                                                               \
        __syncthreads();               /* stage(T) drained (issued a phase ago) */  \
        if ((T) < 31) ISSUE_STAGE((B) ^ 1)                                          \
        _Pragma("unroll") for (int kt = 0; kt < 2; ++kt) {                          \
            bf16x8 kf0 = *(const bf16x8*)(&Ks[B][0] + (kt * 16 + c) * 64 + ((g)     ^ c7) * 8); \
            bf16x8 kf1 = *(const bf16x8*)(&Ks[B][0] + (kt * 16 + c) * 64 + ((4 + g) ^ c7) * 8); \
            f32x4 sc = {};                                                          \
            sc = __builtin_amdgcn_mfma_f32_16x16x32_bf16(kf0, qfx0, sc, 0, 0, 0);   \
            sc = __builtin_amdgcn_mfma_f32_16x16x32_bf16(kf1, qfx1, sc, 0, 0, 0);   \
            f32x4 m4  = *(const f32x4*)(mkP + kt * 16 + g * 4);                     \
            f32x4 lk4 = *(const f32x4*)(&Ls[B][0] + (wid * 16 + c) * 32 + ((kt * 4 + g) ^ c7) * 4); \
            float e0 = vexp2(sc[0] + m4[0]);                                        \
            float e1 = vexp2(sc[1] + m4[1]);                                        \
            float e2 = vexp2(sc[2] + m4[2]);                                        \
            float e3 = vexp2(sc[3] + m4[3]);                                        \
            lsum += (e0 + e1) + (e2 + e3);                                          \
            U32x2 pw;                                                               \
            pw.x = cvtpk(e0 * lk4[0], e1 * lk4[1]);                                 \
            pw.y = cvtpk(e2 * lk4[2], e3 * lk4[3]);                                 \
            *(U32x2*)(Pb + c * 32 + (((kt * 4 + g) ^ (s2 << 1)) * 4)) = pw;         \
        }                                                                           \
        __builtin_amdgcn_s_setprio(1);                                              \
        bf16x8 pf = *(const bf16x8*)(Pb + c * 32 + ((g ^ s2) * 8));                 \
        _Pragma("unroll") for (int dt = 0; dt < 4; ++dt) {                          \
            bf16x8 vf = *(const bf16x8*)(&Vs[B][0] + (dt * 16 + c) * 32 + ((g ^ s2) * 8)); \
            ctx[dt] = __builtin_amdgcn_mfma_f32_16x16x32_bf16(pf, vf, ctx[dt], 0, 0, 0); \
        }                                                                           \
        __builtin_amdgcn_s_setprio(0);                                              \
        mkP += 32;                                                                  \
    }

    ISSUE_STAGE(0)                    // prologue: tile 0 -> buffer 0

    for (int it = 0; it < 16; ++it) {
        ATILE(0, it * 2);
        ATILE(1, it * 2 + 1);
    }
#undef ATILE
#undef ISSUE_STAGE
#undef AS3
#undef AS1

    lsum += __shfl_xor(lsum, 16, 64);
    lsum += __shfl_xor(lsum, 32, 64);

    #pragma unroll
    for (int r = 0; r < 4; ++r) {
        float inv = 1.0f / __shfl(lsum, g * 4 + r, 16);
        int q = qbase + g * 4 + r;
        float* orow = out + (size_t)b * 1048576 + (size_t)q * 1024 + h * 64;
        #pragma unroll
        for (int dt = 0; dt < 4; ++dt)
            orow[dt * 16 + c] = ctx[dt][r] * inv;
    }
}

extern "C" void kernel_launch(void* const* d_in, const int* in_sizes, int n_in,
                              void* d_out, int out_size, void* d_ws, size_t ws_size,
                              hipStream_t stream)
{
    (void)in_sizes; (void)n_in; (void)out_size; (void)ws_size;
    const float* hs    = (const float*)d_in[0];
    const float* amask = (const float*)d_in[1];
    const float* link  = (const float*)d_in[2];
    const float* Wq    = (const float*)d_in[3];
    const float* bq    = (const float*)d_in[4];
    const float* Wk    = (const float*)d_in[5];
    const float* bk    = (const float*)d_in[6];
    const float* Wv    = (const float*)d_in[7];
    const float* bv    = (const float*)d_in[8];
    float* out = (float*)d_out;

    char* ws = (char*)d_ws;
    u16* hsb = (u16*)ws;                   // 8 MiB  [4096][1024] bf16
    u16* wb  = (u16*)(ws + (8u  << 20));   // 6 MiB  [3072][1024] bf16 (Wq|Wk|Wv)
    u16* Qb  = (u16*)(ws + (14u << 20));   // 8 MiB  [B,H,S,64]  (pre-scaled)
    u16* Kb  = (u16*)(ws + (22u << 20));   // 8 MiB  [B,H,S,64]
    u16* Vtb = (u16*)(ws + (30u << 20));   // 8 MiB  [B,H,64,S]
    float* amask2 = (float*)(ws + (38u << 20));  // 16 KB scaled mask

    cvt_kernel<<<7169, 256, 0, stream>>>(hs, Wq, Wk, Wv, amask, hsb, wb, amask2);
    qkv_gemm<<<dim3(24, 32), 256, 0, stream>>>(hsb, wb, bq, bk, bv, Qb, Kb, Vtb);
    attn_kernel<<<1024, 256, 0, stream>>>(Qb, Kb, Vtb, amask2, link, out);
}

// Round 16
// 86.372 us; speedup vs baseline: 1.3851x; 1.0049x over previous
//
#include <hip/hip_runtime.h>
#include <hip/hip_bf16.h>
#include <cstdint>

typedef __attribute__((ext_vector_type(8))) __bf16 bf16x8;
typedef __attribute__((ext_vector_type(4))) float f32x4;
typedef __attribute__((ext_vector_type(16))) float f32x16;
typedef unsigned short u16;
typedef unsigned int u32;

struct alignas(8) U16x4 { u16 x, y, z, w; };
struct alignas(16) U32x4 { u32 x, y, z, w; };

__device__ __forceinline__ u16 f2b(float x) {
    u32 u = __builtin_bit_cast(u32, x);
    u += 0x7fffu + ((u >> 16) & 1u);   // round-to-nearest-even
    return (u16)(u >> 16);
}
__device__ __forceinline__ u32 cvtpk(float lo, float hi) {
    u32 r;
    asm("v_cvt_pk_bf16_f32 %0, %1, %2" : "=v"(r) : "v"(lo), "v"(hi));
    return r;
}
__device__ __forceinline__ float vexp2(float x) {   // raw v_exp_f32 (native 2^x)
    float r;
    asm("v_exp_f32 %0, %1" : "=v"(r) : "v"(x));
    return r;
}
// swap lanes 32-63 of a with lanes 0-31 of b (v_permlane32_swap_b32)
__device__ __forceinline__ void plswap(u32& a, u32& b) {
    asm("v_permlane32_swap_b32 %0, %1" : "+v"(a), "+v"(b));
}

#define LOG2E 1.44269504088896f

// ---------------- kernel 1: f32 -> bf16 convert (hidden + concat weights) ----
// extra last block pre-scales the additive mask by log2(e) (for exp2 in attn).
__global__ __launch_bounds__(256) void cvt_kernel(
    const float* __restrict__ hs,
    const float* __restrict__ wq, const float* __restrict__ wk, const float* __restrict__ wv,
    const float* __restrict__ amask,
    u16* __restrict__ hsb, u16* __restrict__ wb, float* __restrict__ amask2)
{
    if (blockIdx.x == 7168) {          // 4096 floats = 1024 float4 chunks
        int t = threadIdx.x;
        #pragma unroll
        for (int j = 0; j < 4; ++j) {
            float4 v = ((const float4*)amask)[t + j * 256];
            v.x *= LOG2E; v.y *= LOG2E; v.z *= LOG2E; v.w *= LOG2E;
            ((float4*)amask2)[t + j * 256] = v;
        }
        return;
    }
    int i = blockIdx.x * 256 + threadIdx.x;       // float4 chunk index, exact grid
    const float4* src; u16* dst; int off;
    if (i < 1048576) { src = (const float4*)hs; dst = hsb; off = i; }
    else {
        int j = i - 1048576;                      // 3 * 262144 chunks
        int w = j >> 18;
        int o = j & 262143;
        src = (const float4*)(w == 0 ? wq : (w == 1 ? wk : wv));
        dst = wb + w * 1048576;
        off = o;
    }
    float4 v = src[off];
    U16x4 r; r.x = f2b(v.x); r.y = f2b(v.y); r.z = f2b(v.z); r.w = f2b(v.w);
    *(U16x4*)(dst + off * 4) = r;
}

// ---------------- kernel 2: QKV GEMM  C[4096,3072] = A[4096,1024] * W[3072,1024]^T
// BK=32 double-buffered global_load_lds, {barrier; stage(t+1); compute(t)} loop.
// Q pre-scaled by 0.125*log2(e) (exp2 trick); V written transposed. ~27-31 us.
__global__ __launch_bounds__(256, 3) void qkv_gemm(
    const u16* __restrict__ A, const u16* __restrict__ W,
    const float* __restrict__ bq, const float* __restrict__ bk, const float* __restrict__ bv,
    u16* __restrict__ Qo, u16* __restrict__ Ko, u16* __restrict__ Vt)
{
    __shared__ u16 As[2][128 * 32];   // 8 KB per buffer
    __shared__ u16 Bs[2][128 * 32];
    const int tid = threadIdx.x;
    const int lane = tid & 63, wid = tid >> 6;
    const int wr = (wid >> 1) * 64, wc = (wid & 1) * 64;  // wave sub-tile origin
    const int g = lane >> 4, c = lane & 15;

    int lin = blockIdx.y * 24 + blockIdx.x;
    int wg = (lin & 7) * 96 + (lin >> 3);
    const int bn = wg >> 5;      // 0..23
    const int bm = wg & 31;      // 0..31

    f32x4 acc[4][4] = {};

#define GSTAGE(bf, k0)                                                              \
    {                                                                               \
        _Pragma("unroll") for (int i = 0; i < 2; ++i) {                             \
            int chunk = i * 256 + tid;                                              \
            int row = chunk >> 2, col = (chunk & 3) * 8;                            \
            const u16* ga = A + (bm * 128 + row) * 1024 + (k0) + col;               \
            const u16* gb = W + (bn * 128 + row) * 1024 + (k0) + col;               \
            u16* la = &As[bf][0] + (i * 256 + wid * 64) * 8;                        \
            u16* lb = &Bs[bf][0] + (i * 256 + wid * 64) * 8;                        \
            __builtin_amdgcn_global_load_lds((const __attribute__((address_space(1))) u32*)ga, \
                                             (__attribute__((address_space(3))) u32*)la, 16, 0, 0); \
            __builtin_amdgcn_global_load_lds((const __attribute__((address_space(1))) u32*)gb, \
                                             (__attribute__((address_space(3))) u32*)lb, 16, 0, 0); \
        }                                                                           \
    }

    GSTAGE(0, 0);

    int cur = 0;
    for (int t = 0; t < 32; ++t) {
        __syncthreads();              // stage(t) drained (issued one phase ago)
        if (t < 31) GSTAGE(cur ^ 1, (t + 1) * 32);   // overlaps compute below
        bf16x8 af[4], bf4[4];
        #pragma unroll
        for (int i = 0; i < 4; ++i)
            af[i] = *(const bf16x8*)(&As[cur][0] + (wr + i * 16 + c) * 32 + g * 8);
        #pragma unroll
        for (int j = 0; j < 4; ++j)
            bf4[j] = *(const bf16x8*)(&Bs[cur][0] + (wc + j * 16 + c) * 32 + g * 8);
        #pragma unroll
        for (int i = 0; i < 4; ++i)
            #pragma unroll
            for (int j = 0; j < 4; ++j)
                acc[i][j] = __builtin_amdgcn_mfma_f32_16x16x32_bf16(af[i], bf4[j], acc[i][j], 0, 0, 0);
        cur ^= 1;
    }
#undef GSTAGE

    const int region = bn >> 3;                      // 0=Q 1=K 2=V
    const float* bias = region == 0 ? bq : (region == 1 ? bk : bv);
    #pragma unroll
    for (int i = 0; i < 4; ++i) {
        int m0 = bm * 128 + wr + i * 16 + g * 4;
        int b = m0 >> 10, s0 = m0 & 1023;
        #pragma unroll
        for (int j = 0; j < 4; ++j) {
            int n = (bn & 7) * 128 + wc + j * 16 + c;
            float bb = bias[n];
            int h = n >> 6, d = n & 63;
            int bh = b * 16 + h;
            if (region == 2) {
                U16x4 pk;
                pk.x = f2b(acc[i][j][0] + bb);
                pk.y = f2b(acc[i][j][1] + bb);
                pk.z = f2b(acc[i][j][2] + bb);
                pk.w = f2b(acc[i][j][3] + bb);
                *(U16x4*)(Vt + (bh * 64 + d) * 1024 + s0) = pk;
            } else if (region == 1) {
                #pragma unroll
                for (int r = 0; r < 4; ++r)
                    Ko[(bh * 1024 + s0 + r) * 64 + d] = f2b(acc[i][j][r] + bb);
            } else {
                #pragma unroll
                for (int r = 0; r < 4; ++r)   // fold 1/sqrt(D) * log2(e) into Q
                    Qo[(bh * 1024 + s0 + r) * 64 + d] = f2b((acc[i][j][r] + bb) * (0.125f * LOG2E));
            }
        }
    }
}

// ---------------- kernel 3: fused attention, post-softmax multiplicative link mask
// Round-16: 32x32x16 MFMA restructure (T12 path). 512 blocks x 4 waves x 32
// q-rows (128 q/block), kv-tiles of 32, 2 blocks/CU. Swapped QK: D[key][q] has
// col=q=lane&31, rows=keys scattered by reg: k(r,hi)=(r&3)+8*(r>>2)+4*hi.
// P NEVER TOUCHES LDS: PV's B-frag (keys hi*8..hi*8+7) is assembled from the QK
// output by 8 cvt_pk_bf16 + 4 v_permlane32_swap_b32 (swap(cvtpk(p0,p1),
// cvtpk(p4,p5)) -> words w0,w2; p2,p3/p6,p7 -> w1,w3; p8..15 -> keys 16-31).
// K/V/link LDS reads per q-row HALVE vs 16x16 (frag bytes scale with kxd).
// K [32k][64d] swizzle chunk^=(row&7); V [64d][32k] chunk^=((row>>1)&3);
// link f32 [128q][32k] LDS-dbuf, chunk^=(row&7). lsum: one shfl_xor(32).
__global__ __launch_bounds__(256, 2) void attn_kernel(
    const u16* __restrict__ Q, const u16* __restrict__ K, const u16* __restrict__ Vt,
    const float* __restrict__ amask, const float* __restrict__ link,
    float* __restrict__ out)
{
    __shared__ u16 Ks[2][32 * 64];     // 4 KB per buffer
    __shared__ u16 Vs[2][64 * 32];     // 4 KB per buffer
    __shared__ float Ls[2][128 * 32];  // 16 KB per buffer (link f32)
    const int tid = threadIdx.x;
    const int lane = tid & 63, wid = tid >> 6;
    const int c5 = lane & 31, hi = lane >> 5;
    const int c7 = c5 & 7;
    const int s2 = (c5 >> 1) & 3;

    // XCD swizzle: 512 blocks; XCD x owns logical x*64..x*64+63.
    int hw = blockIdx.x;
    int logical = (hw & 7) * 64 + (hw >> 3);
    int b = logical >> 7;              // [0,4)
    int qt = (logical >> 4) & 7;       // [0,8) tiles of 128 q-rows
    int h = logical & 15;
    int bh = b * 16 + h;
    const int qbase = qt * 128 + wid * 32;

    const u16* Qh = Q + bh * 65536;
    const u16* Kh = K + bh * 65536;
    const u16* Vh = Vt + bh * 65536;
    const float* mkP = amask + b * 1024;           // advances 32/tile (log2e-scaled)
    const float* Lq = link + (size_t)b * 1048576 + (size_t)(qt * 128) * 1024;

    bf16x8 qf[4];
    #pragma unroll
    for (int m = 0; m < 4; ++m)
        qf[m] = *(const bf16x8*)(Qh + (qbase + c5) * 64 + m * 16 + hi * 8);

    float lsum = 0.f;
    f32x16 ctx0 = {}, ctx1 = {};

    // staging roles (loop-invariant); sources pre-swizzled (rule #21)
    const int krow = tid >> 3;
    const int vrow = tid >> 2;
    const int lrow = tid >> 3;
    const u16* gk  = Kh + krow * 64 + (((tid & 7) ^ (krow & 7)) * 8);        // +=2048
    const u16* gv  = Vh + vrow * 1024 + (((tid & 3) ^ ((vrow >> 1) & 3)) * 8); // +=32
    const int lcir = (tid & 7) ^ (lrow & 7);
    const float* gl0 = Lq + (lrow +  0) * 1024 + lcir * 4;                   // +=32
    const float* gl1 = Lq + (lrow + 32) * 1024 + lcir * 4;
    const float* gl2 = Lq + (lrow + 64) * 1024 + lcir * 4;
    const float* gl3 = Lq + (lrow + 96) * 1024 + lcir * 4;

#define AS3(p) (__attribute__((address_space(3))) u32*)(p)
#define AS1(p) (const __attribute__((address_space(1))) u32*)(p)
#define ISSUE_STAGE(B)                                                              \
    {                                                                               \
        __builtin_amdgcn_global_load_lds(AS1(gk),  AS3(&Ks[B][0] + wid * 512), 16, 0, 0); \
        __builtin_amdgcn_global_load_lds(AS1(gv),  AS3(&Vs[B][0] + wid * 512), 16, 0, 0); \
        __builtin_amdgcn_global_load_lds(AS1(gl0), AS3(&Ls[B][0] +        wid * 256), 16, 0, 0); \
        __builtin_amdgcn_global_load_lds(AS1(gl1), AS3(&Ls[B][0] + 1024 + wid * 256), 16, 0, 0); \
        __builtin_amdgcn_global_load_lds(AS1(gl2), AS3(&Ls[B][0] + 2048 + wid * 256), 16, 0, 0); \
        __builtin_amdgcn_global_load_lds(AS1(gl3), AS3(&Ls[B][0] + 3072 + wid * 256), 16, 0, 0); \
        gk += 2048; gv += 32; gl0 += 32; gl1 += 32; gl2 += 32; gl3 += 32;           \
    }

#define ATILE(B, T)                                                                 \
    {                                                                               \
        __syncthreads();               /* stage(T) drained (issued a phase ago) */  \
        if ((T) < 31) ISSUE_STAGE((B) ^ 1)                                          \
        f32x16 sc = {};                                                             \
        _Pragma("unroll") for (int m = 0; m < 4; ++m) {                             \
            bf16x8 kf = *(const bf16x8*)(&Ks[B][0] + c5 * 64 + (((2 * m + hi) ^ c7) * 8)); \
            sc = __builtin_amdgcn_mfma_f32_32x32x16_bf16(kf, qf[m], sc, 0, 0, 0);   \
        }                                                                           \
        f32x4 mq[4], lq[4];                                                         \
        _Pragma("unroll") for (int j = 0; j < 4; ++j) {                             \
            mq[j] = *(const f32x4*)(mkP + j * 8 + hi * 4);                          \
            lq[j] = *(const f32x4*)(&Ls[B][0] + (wid * 32 + c5) * 32 + (((2 * j + hi) ^ c7) * 4)); \
        }                                                                           \
        float p[16];                                                                \
        _Pragma("unroll") for (int r = 0; r < 16; ++r) {                            \
            float e = vexp2(sc[r] + mq[r >> 2][r & 3]);                             \
            lsum += e;                                                              \
            p[r] = e * lq[r >> 2][r & 3];                                           \
        }                                                                           \
        u32 a0 = cvtpk(p[0], p[1]),   b0 = cvtpk(p[4], p[5]);                       \
        u32 a1 = cvtpk(p[2], p[3]),   b1 = cvtpk(p[6], p[7]);                       \
        u32 a2 = cvtpk(p[8], p[9]),   b2 = cvtpk(p[12], p[13]);                     \
        u32 a3 = cvtpk(p[10], p[11]), b3 = cvtpk(p[14], p[15]);                     \
        plswap(a0, b0); plswap(a1, b1); plswap(a2, b2); plswap(a3, b3);             \
        U32x4 w0 = {a0, a1, b0, b1}, w1 = {a2, a3, b2, b3};                         \
        bf16x8 pa0 = __builtin_bit_cast(bf16x8, w0);   /* keys  0-15 frag */        \
        bf16x8 pa1 = __builtin_bit_cast(bf16x8, w1);   /* keys 16-31 frag */        \
        __builtin_amdgcn_s_setprio(1);                                              \
        {                                                                           \
            bf16x8 v00 = *(const bf16x8*)(&Vs[B][0] + c5 * 32 + (((0 + hi) ^ s2) * 8)); \
            bf16x8 v01 = *(const bf16x8*)(&Vs[B][0] + c5 * 32 + (((2 + hi) ^ s2) * 8)); \
            bf16x8 v10 = *(const bf16x8*)(&Vs[B][0] + (32 + c5) * 32 + (((0 + hi) ^ s2) * 8)); \
            bf16x8 v11 = *(const bf16x8*)(&Vs[B][0] + (32 + c5) * 32 + (((2 + hi) ^ s2) * 8)); \
            ctx0 = __builtin_amdgcn_mfma_f32_32x32x16_bf16(v00, pa0, ctx0, 0, 0, 0); \
            ctx1 = __builtin_amdgcn_mfma_f32_32x32x16_bf16(v10, pa0, ctx1, 0, 0, 0); \
            ctx0 = __builtin_amdgcn_mfma_f32_32x32x16_bf16(v01, pa1, ctx0, 0, 0, 0); \
            ctx1 = __builtin_amdgcn_mfma_f32_32x32x16_bf16(v11, pa1, ctx1, 0, 0, 0); \
        }                                                                           \
        __builtin_amdgcn_s_setprio(0);                                              \
        mkP += 32;                                                                  \
    }

    ISSUE_STAGE(0)                    // prologue: tile 0 -> buffer 0

    for (int it = 0; it < 16; ++it) {
        ATILE(0, it * 2);
        ATILE(1, it * 2 + 1);
    }
#undef ATILE
#undef ISSUE_STAGE
#undef AS3
#undef AS1

    lsum += __shfl_xor(lsum, 32, 64);  // combine the two key-halves of q=c5
    float inv = 1.0f / lsum;

    float* orow = out + (size_t)b * 1048576 + (size_t)(qbase + c5) * 1024 + h * 64;
    #pragma unroll
    for (int rq = 0; rq < 4; ++rq) {
        f32x4 o0 = { ctx0[rq * 4 + 0] * inv, ctx0[rq * 4 + 1] * inv,
                     ctx0[rq * 4 + 2] * inv, ctx0[rq * 4 + 3] * inv };
        f32x4 o1 = { ctx1[rq * 4 + 0] * inv, ctx1[rq * 4 + 1] * inv,
                     ctx1[rq * 4 + 2] * inv, ctx1[rq * 4 + 3] * inv };
        *(f32x4*)(orow + rq * 8 + hi * 4)      = o0;   // d = rq*8+4hi+0..3
        *(f32x4*)(orow + 32 + rq * 8 + hi * 4) = o1;   // d = 32+...
    }
}

extern "C" void kernel_launch(void* const* d_in, const int* in_sizes, int n_in,
                              void* d_out, int out_size, void* d_ws, size_t ws_size,
                              hipStream_t stream)
{
    (void)in_sizes; (void)n_in; (void)out_size; (void)ws_size;
    const float* hs    = (const float*)d_in[0];
    const float* amask = (const float*)d_in[1];
    const float* link  = (const float*)d_in[2];
    const float* Wq    = (const float*)d_in[3];
    const float* bq    = (const float*)d_in[4];
    const float* Wk    = (const float*)d_in[5];
    const float* bk    = (const float*)d_in[6];
    const float* Wv    = (const float*)d_in[7];
    const float* bv    = (const float*)d_in[8];
    float* out = (float*)d_out;

    char* ws = (char*)d_ws;
    u16* hsb = (u16*)ws;                   // 8 MiB  [4096][1024] bf16
    u16* wb  = (u16*)(ws + (8u  << 20));   // 6 MiB  [3072][1024] bf16 (Wq|Wk|Wv)
    u16* Qb  = (u16*)(ws + (14u << 20));   // 8 MiB  [B,H,S,64]  (pre-scaled)
    u16* Kb  = (u16*)(ws + (22u << 20));   // 8 MiB  [B,H,S,64]
    u16* Vtb = (u16*)(ws + (30u << 20));   // 8 MiB  [B,H,64,S]
    float* amask2 = (float*)(ws + (38u << 20));  // 16 KB scaled mask

    cvt_kernel<<<7169, 256, 0, stream>>>(hs, Wq, Wk, Wv, amask, hsb, wb, amask2);
    qkv_gemm<<<dim3(24, 32), 256, 0, stream>>>(hsb, wb, bq, bk, bv, Qb, Kb, Vtb);
    attn_kernel<<<512, 256, 0, stream>>>(Qb, Kb, Vtb, amask2, link, out);
}